// Round 9
// baseline (522.553 us; speedup 1.0000x reference)
//
#include <hip/hip_runtime.h>
#include <math.h>

#define NN    50000
#define DD    64
#define HH    4
#define E_RES 400000
#define E_SEQ 100000
#define E_KNN 400000
#define ETOT  (E_RES+E_SEQ+E_KNN)
#define RPS   (NN + 4)               // rowptr stride (16B-aligned per relation)
#define NBLK  ((NN+255)/256)         // 196
#define KTOT  864                    // fused matmul K: 64 (x) + 800 (z+flags+pad)
#define CTPS  (ETOT + 32)            // coefT per-head plane stride (shorts)
#define NBUK  98                     // buckets per relation (512 dsts each)
#define TBUK  (3*NBUK)               // 294 total buckets
#define EPB   4096                   // edges per block in partition kernels
#define PABLK ((ETOT+EPB-1)/EPB)     // 220
#define FBLK  (NN/16)                // 3125 fused blocks (16 nodes each)
#define ECB   ((3*NN)/4)             // 37500 edgecoef blocks (4 waves each)
#define LZS   810                    // LDS Z stride in shorts (405 dwords, odd -> bank-safe)

typedef __attribute__((ext_vector_type(8))) short short8;
typedef __attribute__((ext_vector_type(4))) float floatx4;

__device__ inline unsigned short f2bf(float f){
  union{float f; unsigned u;} v; v.f=f;
  unsigned r = v.u + 0x7FFF + ((v.u>>16)&1);
  return (unsigned short)(r>>16);
}
__device__ inline float bf2f(unsigned short u){
  union{unsigned u; float f;} v; v.u=(unsigned)u<<16; return v.f;
}

// ---------------- bucketed CSR build --------------------------------------
__global__ void __launch_bounds__(256)
k_bucketcnt(const int* __restrict__ d0, const int* __restrict__ d1,
            const int* __restrict__ d2, int* __restrict__ bcnt){
  __shared__ int cnt[TBUK];
  int t = threadIdx.x;
  for(int i=t;i<TBUK;i+=256) cnt[i]=0;
  __syncthreads();
  int ebase = blockIdx.x*EPB;
  #pragma unroll
  for(int j=0;j<16;j++){
    int i = ebase + j*256 + t;
    int d, r;
    if(i < E_RES){ d=d0[i]; r=0; }
    else if(i < E_RES+E_SEQ){ d=d1[i-E_RES]; r=1; }
    else if(i < ETOT){ d=d2[i-E_RES-E_SEQ]; r=2; }
    else continue;
    atomicAdd(&cnt[r*NBUK + (d>>9)], 1);
  }
  __syncthreads();
  for(int i=t;i<TBUK;i+=256){ int c=cnt[i]; if(c) atomicAdd(&bcnt[i], c); }
}

__global__ void k_bucketscan(const int* __restrict__ bcnt,
                             int* __restrict__ bbase, int* __restrict__ bcur){
  __shared__ int sh[TBUK];
  int t = threadIdx.x;
  if(t < 64){
    int carry = 0;
    for(int c=0;c<5;c++){
      int idx = c*64 + t;
      int v = (idx < TBUK) ? bcnt[idx] : 0;
      int inc = v;
      for(int off=1; off<64; off<<=1){ int n=__shfl_up(inc, off, 64); if(t>=off) inc+=n; }
      if(idx < TBUK) sh[idx] = carry + inc - v;   // exclusive
      carry += __shfl(inc, 63, 64);
    }
  }
  __syncthreads();
  if(t < TBUK){ bbase[t] = sh[t]; bcur[t] = sh[t]; }
  if(t == 0) bbase[TBUK] = ETOT;
}

// partition edges into bucket regions as packed (dloc<<16 | src) u32
__global__ void __launch_bounds__(256)
k_partA(const int* __restrict__ s0, const int* __restrict__ d0,
        const int* __restrict__ s1, const int* __restrict__ d1,
        const int* __restrict__ s2, const int* __restrict__ d2,
        int* __restrict__ bcur, unsigned* __restrict__ pairs){
  __shared__ int cnt[TBUK];
  __shared__ int gb[TBUK];
  int t = threadIdx.x;
  for(int i=t;i<TBUK;i+=256) cnt[i]=0;
  __syncthreads();
  int ebase = blockIdx.x*EPB;
  unsigned meta[16], pk[16];
  #pragma unroll
  for(int j=0;j<16;j++){
    int i = ebase + j*256 + t;
    int s, d, r;
    if(i < E_RES){ s=s0[i]; d=d0[i]; r=0; }
    else if(i < E_RES+E_SEQ){ int k=i-E_RES; s=s1[k]; d=d1[k]; r=1; }
    else if(i < ETOT){ int k=i-E_RES-E_SEQ; s=s2[k]; d=d2[k]; r=2; }
    else { meta[j]=0xFFFFFFFFu; continue; }
    int bk = r*NBUK + (d>>9);
    int rk = atomicAdd(&cnt[bk], 1);
    meta[j] = ((unsigned)bk<<16) | (unsigned)rk;   // bk<294, rk<4096
    pk[j]   = ((unsigned)(d&511)<<16) | (unsigned)s;  // src < 65536
  }
  __syncthreads();
  for(int i=t;i<TBUK;i+=256){ int c=cnt[i]; gb[i] = c ? atomicAdd(&bcur[i], c) : 0; }
  __syncthreads();
  #pragma unroll
  for(int j=0;j<16;j++){
    unsigned mt = meta[j];
    if(mt != 0xFFFFFFFFu)
      pairs[gb[mt>>16] + (mt & 0xFFFFu)] = pk[j];
  }
}

// per-bucket: LDS per-dst histogram -> rowptr slice + localized csr scatter
__global__ void __launch_bounds__(256)
k_partB(const unsigned* __restrict__ pairs, const int* __restrict__ bbase,
        int* __restrict__ rowptr, int* __restrict__ csr){
  int bb = blockIdx.x, r = bb / NBUK, b = bb - r*NBUK;
  int dbase = b*512, dmax = min(512, NN - dbase);
  int off = (r==0)?0:(r==1)?E_RES:(E_RES+E_SEQ);
  __shared__ int hist[512];
  __shared__ int curs[513];
  int t = threadIdx.x;
  hist[t]=0; hist[256+t]=0;
  __syncthreads();
  int beg = bbase[bb], end = bbase[bb+1];
  for(int i=beg+t; i<end; i+=256) atomicAdd(&hist[pairs[i]>>16], 1);
  __syncthreads();
  if(t < 64){
    int carry = 0;
    for(int c=0;c<8;c++){
      int v = hist[c*64+t];
      int inc = v;
      for(int o2=1; o2<64; o2<<=1){ int n=__shfl_up(inc, o2, 64); if(t>=o2) inc+=n; }
      curs[c*64+t] = (beg - off) + carry + inc - v;   // exclusive, relation-local
      carry += __shfl(inc, 63, 64);
    }
    if(t==0) curs[512] = end - off;
  }
  __syncthreads();
  int* rp = rowptr + r*RPS + dbase;
  for(int i=t; i<=dmax; i+=256) rp[i] = curs[i];
  __syncthreads();
  for(int i=beg+t; i<end; i+=256){
    unsigned p = pairs[i];
    int pos = atomicAdd(&curs[p>>16], 1);
    csr[off + pos] = (int)(p & 0xFFFFu);
  }
}

// ---------------- BN stats + bf16 cast (layer 1 input) ----------------------
__global__ void k_bnstats(const float* __restrict__ x, float* __restrict__ stats,
                          unsigned short* __restrict__ Abf){
  __shared__ float sh[512];
  int t = threadIdx.x, col = t & 63, rg = t >> 6;
  float s=0.f, q=0.f;
  for(int row = blockIdx.x*4 + rg; row < NN; row += gridDim.x*4){
    float v = x[(size_t)row*64 + col]; s += v; q += v*v;
    Abf[(size_t)row*64 + col] = f2bf(v);
  }
  sh[t]=s; sh[256+t]=q; __syncthreads();
  if(rg==0){
    s = sh[col]+sh[64+col]+sh[128+col]+sh[192+col];
    q = sh[256+col]+sh[320+col]+sh[384+col]+sh[448+col];
    atomicAdd(&stats[col], s); atomicAdd(&stats[64+col], q);
  }
}

// ---------------- prep: build fused weights ---------------------------------
// Z K-layout (shorts within a node row): [r][d][h]  (d = z input dim, h = head)
// => K index for z element = 64 + r*256 + d*4 + h.  Flags at 832+r. Pad zero.
__global__ void __launch_bounds__(256)
k_prep3(const float* __restrict__ stats, const float* __restrict__ g,
        const float* __restrict__ be, const float* __restrict__ W,
        const float* __restrict__ al, const float* __restrict__ ar,
        const float* __restrict__ b, const float* __restrict__ rW,
        const float* __restrict__ fcW, const float* __restrict__ fcb,
        float* __restrict__ wbufF){
  __shared__ float scale[64], shift[64];
  int t = threadIdx.x;
  if(t<64){
    float mu  = stats[t]*(1.0f/NN);
    float var = stats[64+t]*(1.0f/NN) - mu*mu;
    float sc  = g[t]*rsqrtf(var + 1e-5f);
    scale[t]=sc; shift[t]=be[t]-mu*sc;
  }
  __syncthreads();
  char* wb = (char*)wbufF;
  unsigned short* Wf = (unsigned short*)wbufF;
  float* biasF = (float*)(wb + 110592);
  int bid = blockIdx.x;
  if(bid < 52){
    __shared__ float fcWs[4096];
    for(int i=t;i<4096;i+=256) fcWs[i]=fcW[i];
    __syncthreads();
    int j = bid*16 + (t>>4);
    int cg = (t&15)*4;
    float Wrow[64];
    if(j < 64){
      for(int d=0; d<64; d++){
        float w=0.f;
        for(int r=0;r<3;r++)
          #pragma unroll
          for(int h=0;h<4;h++)
            w += rW[((size_t)(r*64+j))*256 + h*64 + d];
        Wrow[d] = scale[j]*0.25f*w;
      }
    } else {
      int jj = j-64;
      int r = jj>>8, dc = jj&255, h = dc&3, c = dc>>2;   // [r][d][h] K-layout
      const float* Wp = W + ((size_t)(r*64+c))*256 + h*64;
      float sc = 0.25f*scale[c];
      #pragma unroll
      for(int d=0; d<64; d++) Wrow[d] = sc*Wp[d];
    }
    #pragma unroll
    for(int cc=0; cc<4; cc++){
      int col = cg+cc;
      float acc=0.f;
      #pragma unroll
      for(int d=0; d<64; d++) acc += Wrow[d]*fcWs[d*64+col];
      Wf[(size_t)col*KTOT + j] = f2bf(acc);
    }
  } else if(bid < 58){
    int wv = (bid-52)*4 + (t>>6);        // 0..23
    int r = wv >> 3, cc = wv & 7, h = cc & 3, k = t & 63;
    const float* av = ((cc>=4)?ar:al) + (r*HH+h)*64;
    const float* Wk = W + ((size_t)(r*64+k))*256 + h*64;
    float w=0.f;
    for(int d2=0; d2<64; d2++) w += Wk[d2]*av[d2];
    float* WelR = (float*)(wb + 110848 + r*2080);
    WelR[cc*64 + k] = scale[k]*w;
    float bp = shift[k]*w;
    for(int off=32; off; off>>=1) bp += __shfl_down(bp, off, 64);
    if(k==0) (WelR + 512)[cc] = bp;
  } else {
    __shared__ float S[3][64];
    __shared__ float BH[64];
    if(t<192){
      int r=t>>6, d=t&63;
      float s=0.f;
      #pragma unroll
      for(int h=0;h<4;h++){
        const float* Wp = W + (size_t)(r*64)*256 + h*64 + d;
        for(int k=0;k<64;k++) s += shift[k]*Wp[(size_t)k*256];
      }
      S[r][d]=0.25f*s;
    } else {
      int d = t-192;
      float s=0.f;
      for(int k=0;k<64;k++){
        float w=0.f;
        for(int r=0;r<3;r++)
          #pragma unroll
          for(int h=0;h<4;h++)
            w += rW[((size_t)(r*64+k))*256 + h*64 + d];
        s += shift[k]*0.25f*w;
      }
      float bb=0.f;
      for(int r=0;r<3;r++)
        #pragma unroll
        for(int h=0;h<4;h++) bb += b[r*256 + h*64 + d];
      BH[d] = s + 0.25f*bb;
    }
    __syncthreads();
    if(t<192){
      int r=t>>6, col=t&63;
      float acc=0.f;
      for(int d=0;d<64;d++) acc += S[r][d]*fcW[d*64+col];
      Wf[(size_t)col*KTOT + 832 + r] = f2bf(acc);
    } else {
      int col=t-192;
      float acc=0.f;
      for(int d=0;d<64;d++) acc += BH[d]*fcW[d*64+col];
      biasF[col] = acc + fcb[col];
    }
    if(t<64){
      for(int j=835;j<KTOT;j++) Wf[(size_t)t*KTOT + j] = 0;
    }
  }
}

// ---------------- el/er (all 3 relations): EL[r][N,8] -----------------------
__global__ void __launch_bounds__(256)
k_el3(const float* __restrict__ A, const float* __restrict__ wbufF,
      float* __restrict__ EL){
  int r = blockIdx.x / NBLK;
  const char* wb = (const char*)wbufF;
  const float* Wel = (const float*)(wb + 110848 + r*2080);
  const float* biasE = Wel + 512;
  float* ELr = EL + (size_t)r*NN*8;
  __shared__ float sw[512];
  __shared__ float sb[8];
  int t = threadIdx.x;
  sw[t]=Wel[t]; sw[256+t]=Wel[256+t];
  if(t<8) sb[t]=biasE[t];
  __syncthreads();
  int n = (blockIdx.x % NBLK)*256 + t;
  if(n>=NN) return;
  float acc[8];
  #pragma unroll
  for(int c=0;c<8;c++) acc[c]=sb[c];
  const float4* Ar = (const float4*)(A + (size_t)n*64);
  #pragma unroll
  for(int kq=0;kq<16;kq++){
    float4 a = Ar[kq];
    #pragma unroll
    for(int c=0;c<8;c++){
      const float* w = sw + c*64 + kq*4;
      acc[c] += a.x*w[0] + a.y*w[1] + a.z*w[2] + a.w*w[3];
    }
  }
  ((float4*)ELr)[n*2]   = make_float4(acc[0],acc[1],acc[2],acc[3]);
  ((float4*)ELr)[n*2+1] = make_float4(acc[4],acc[5],acc[6],acc[7]);
}

// ---------------- edge coefficients: WAVE per (node, relation) --------------
// Old: 1 thread/node, serial deg-loop, 2 gather passes, 2344 waves total (~3
// waves/CU -> latency-starved). New: 1 wave/(node,relation) = 150000 waves;
// lane e gathers EL[src_e] once, holds e in regs (deg<=64 fast path), cross-
// lane shfl max + sum-of-exp, coalesced bf16 alpha stores. Rare deg>64 falls
// back to chunked online loop.
__global__ void __launch_bounds__(256)
k_edgecoef3(const float* __restrict__ EL, const int* __restrict__ rowptr,
            const int* __restrict__ csr, unsigned short* __restrict__ coefT){
  int w = blockIdx.x*4 + (threadIdx.x>>6);
  int lane = threadIdx.x & 63;
  int r = w / NN, n = w - r*NN;
  const float* ELr = EL + (size_t)r*NN*8;
  const int* rp = rowptr + r*RPS;
  int off = (r==0)?0:(r==1)?E_RES:(E_RES+E_SEQ);
  const int* cs = csr + off;
  unsigned short* t0 = coefT + off;
  unsigned short* t1 = coefT + (size_t)CTPS + off;
  unsigned short* t2 = coefT + (size_t)2*CTPS + off;
  unsigned short* t3 = coefT + (size_t)3*CTPS + off;
  int beg = rp[n], end = rp[n+1];
  int deg = end - beg;
  if(deg <= 0) return;
  const float4 er = ((const float4*)ELr)[n*2+1];
  if(deg <= 64){
    bool act = lane < deg;
    int src = cs[beg + (act ? lane : 0)];
    float4 el = ((const float4*)ELr)[src*2];
    float e0=el.x+er.x, e1=el.y+er.y, e2=el.z+er.z, e3=el.w+er.w;
    e0 = e0>0.f? e0 : 0.2f*e0;
    e1 = e1>0.f? e1 : 0.2f*e1;
    e2 = e2>0.f? e2 : 0.2f*e2;
    e3 = e3>0.f? e3 : 0.2f*e3;
    if(!act){ e0=-1e30f; e1=-1e30f; e2=-1e30f; e3=-1e30f; }
    float m0=e0,m1=e1,m2=e2,m3=e3;
    #pragma unroll
    for(int o=32;o;o>>=1){
      m0=fmaxf(m0,__shfl_xor(m0,o,64));
      m1=fmaxf(m1,__shfl_xor(m1,o,64));
      m2=fmaxf(m2,__shfl_xor(m2,o,64));
      m3=fmaxf(m3,__shfl_xor(m3,o,64));
    }
    float p0=__expf(e0-m0), p1=__expf(e1-m1), p2=__expf(e2-m2), p3=__expf(e3-m3);
    float s0=p0,s1=p1,s2=p2,s3=p3;
    #pragma unroll
    for(int o=32;o;o>>=1){
      s0+=__shfl_xor(s0,o,64);
      s1+=__shfl_xor(s1,o,64);
      s2+=__shfl_xor(s2,o,64);
      s3+=__shfl_xor(s3,o,64);
    }
    if(act){
      int i = beg + lane;
      t0[i]=f2bf(p0/s0); t1[i]=f2bf(p1/s1); t2[i]=f2bf(p2/s2); t3[i]=f2bf(p3/s3);
    }
  } else {
    float m0=-1e30f,m1=-1e30f,m2=-1e30f,m3=-1e30f;
    float s0=0.f,s1=0.f,s2=0.f,s3=0.f;
    for(int i=beg+lane; i<end; i+=64){
      int src = cs[i];
      float4 el = ((const float4*)ELr)[src*2];
      float e0=el.x+er.x, e1=el.y+er.y, e2=el.z+er.z, e3=el.w+er.w;
      e0 = e0>0.f? e0 : 0.2f*e0;
      e1 = e1>0.f? e1 : 0.2f*e1;
      e2 = e2>0.f? e2 : 0.2f*e2;
      e3 = e3>0.f? e3 : 0.2f*e3;
      float n0=fmaxf(m0,e0); s0=s0*__expf(m0-n0)+__expf(e0-n0); m0=n0;
      float n1=fmaxf(m1,e1); s1=s1*__expf(m1-n1)+__expf(e1-n1); m1=n1;
      float n2=fmaxf(m2,e2); s2=s2*__expf(m2-n2)+__expf(e2-n2); m2=n2;
      float n3=fmaxf(m3,e3); s3=s3*__expf(m3-n3)+__expf(e3-n3); m3=n3;
    }
    #pragma unroll
    for(int o=32;o;o>>=1){
      float om,os,nm;
      om=__shfl_xor(m0,o,64); os=__shfl_xor(s0,o,64);
      nm=fmaxf(m0,om); s0=s0*__expf(m0-nm)+os*__expf(om-nm); m0=nm;
      om=__shfl_xor(m1,o,64); os=__shfl_xor(s1,o,64);
      nm=fmaxf(m1,om); s1=s1*__expf(m1-nm)+os*__expf(om-nm); m1=nm;
      om=__shfl_xor(m2,o,64); os=__shfl_xor(s2,o,64);
      nm=fmaxf(m2,om); s2=s2*__expf(m2-nm)+os*__expf(om-nm); m2=nm;
      om=__shfl_xor(m3,o,64); os=__shfl_xor(s3,o,64);
      nm=fmaxf(m3,om); s3=s3*__expf(m3-nm)+os*__expf(om-nm); m3=nm;
    }
    float r0=1.f/s0, r1=1.f/s1, r2=1.f/s2, r3=1.f/s3;
    for(int i=beg+lane; i<end; i+=64){
      int src = cs[i];
      float4 el = ((const float4*)ELr)[src*2];
      float e0=el.x+er.x, e1=el.y+er.y, e2=el.z+er.z, e3=el.w+er.w;
      e0 = e0>0.f? e0 : 0.2f*e0;
      e1 = e1>0.f? e1 : 0.2f*e1;
      e2 = e2>0.f? e2 : 0.2f*e2;
      e3 = e3>0.f? e3 : 0.2f*e3;
      t0[i]=f2bf(__expf(e0-m0)*r0);
      t1[i]=f2bf(__expf(e1-m1)*r1);
      t2[i]=f2bf(__expf(e2-m2)*r2);
      t3[i]=f2bf(__expf(e3-m3)*r3);
    }
  }
}

// ---------------- FUSED aggregation + matmul (r7 best-measured form) --------
// Block = 4 waves = 16 nodes. Phase 1: wave wv aggregates Z for its 4-node
// group across 3 relations via MFMA into LDS (LZS=810 conflict-free). Phase 2:
// wave wv -> col-tile wv, K=864 matmul. ~100us/layer floor measured stable
// across 5 structural variants (occupancy/wave-length/VMEM-count theories all
// falsified) — treat as floor, do not restructure.
__global__ void __launch_bounds__(256)
k_fused(const unsigned short* __restrict__ Abf, const int* __restrict__ rowptr,
        const int* __restrict__ csr, const unsigned short* __restrict__ coefT,
        const float* __restrict__ wbufF, float* __restrict__ out,
        unsigned short* __restrict__ Abf2, float* __restrict__ stats, int dostats){
  __shared__ unsigned short Zl[16*LZS];   // 25920 B
  const unsigned short* Wf = (const unsigned short*)wbufF;
  const float* biasF = (const float*)((const char*)wbufF + 110592);
  int t = threadIdx.x, wv = t>>6, lane = t&63, m = lane&15, kq = lane>>4;
  int nb = blockIdx.x*16;
  int n4 = nb + wv*4;
  int nn = m>>2, h = m&3;
  // zero pad shorts [771,800) of each node row (phase 2 reads shorts [0,800))
  for(int i=t; i<512; i+=256){ int nd=i>>5, j=i&31; if(j<29) Zl[nd*LZS+771+j]=0; }
  // ---- phase 1: aggregation (3 relations sequentially) ----
  for(int r=0;r<3;r++){
    const int* rp = rowptr + r*RPS;
    int off = (r==0)?0:(r==1)?E_RES:(E_RES+E_SEQ);
    const int* cs = csr + off;
    const unsigned short* cT = coefT + (size_t)h*CTPS + off;
    int rpn  = rp[n4+nn];
    int rpn1 = rp[n4+nn+1];
    unsigned dg = (unsigned)(rpn1 - rpn);
    int beg = __shfl(rpn, 0, 64);     // rp[n4]
    int end = __shfl(rpn1, 15, 64);   // rp[n4+4]
    floatx4 acc0={0.f,0.f,0.f,0.f};
    floatx4 acc1={0.f,0.f,0.f,0.f};
    floatx4 acc2={0.f,0.f,0.f,0.f};
    floatx4 acc3={0.f,0.f,0.f,0.f};
    for(int eb = (beg & ~31); eb < end; eb += 32){
      int p0 = eb + kq*8;
      union { uint4 q; short8 v; } af;
      af.q = *(const uint4*)(cT + p0);
      int qd = p0 - rpn;
      unsigned w0 = (((unsigned)(qd+0)<dg)?0x0000FFFFu:0u) | (((unsigned)(qd+1)<dg)?0xFFFF0000u:0u);
      unsigned w1 = (((unsigned)(qd+2)<dg)?0x0000FFFFu:0u) | (((unsigned)(qd+3)<dg)?0xFFFF0000u:0u);
      unsigned w2 = (((unsigned)(qd+4)<dg)?0x0000FFFFu:0u) | (((unsigned)(qd+5)<dg)?0xFFFF0000u:0u);
      unsigned w3 = (((unsigned)(qd+6)<dg)?0x0000FFFFu:0u) | (((unsigned)(qd+7)<dg)?0xFFFF0000u:0u);
      af.q.x &= w0; af.q.y &= w1; af.q.z &= w2; af.q.w &= w3;
      const int* csp = cs + p0;
      int s0=csp[0],s1=csp[1],s2=csp[2],s3=csp[3],s4=csp[4],s5=csp[5],s6=csp[6],s7=csp[7];
      const unsigned short* q0 = Abf + ((size_t)s0<<6) + m;
      const unsigned short* q1 = Abf + ((size_t)s1<<6) + m;
      const unsigned short* q2 = Abf + ((size_t)s2<<6) + m;
      const unsigned short* q3 = Abf + ((size_t)s3<<6) + m;
      const unsigned short* q4 = Abf + ((size_t)s4<<6) + m;
      const unsigned short* q5 = Abf + ((size_t)s5<<6) + m;
      const unsigned short* q6 = Abf + ((size_t)s6<<6) + m;
      const unsigned short* q7 = Abf + ((size_t)s7<<6) + m;
      union { unsigned u[4]; short8 v; } b0,b1,b2,b3;
      b0.u[0]=(unsigned)q0[0] |((unsigned)q1[0]<<16);
      b0.u[1]=(unsigned)q2[0] |((unsigned)q3[0]<<16);
      b0.u[2]=(unsigned)q4[0] |((unsigned)q5[0]<<16);
      b0.u[3]=(unsigned)q6[0] |((unsigned)q7[0]<<16);
      b1.u[0]=(unsigned)q0[16]|((unsigned)q1[16]<<16);
      b1.u[1]=(unsigned)q2[16]|((unsigned)q3[16]<<16);
      b1.u[2]=(unsigned)q4[16]|((unsigned)q5[16]<<16);
      b1.u[3]=(unsigned)q6[16]|((unsigned)q7[16]<<16);
      b2.u[0]=(unsigned)q0[32]|((unsigned)q1[32]<<16);
      b2.u[1]=(unsigned)q2[32]|((unsigned)q3[32]<<16);
      b2.u[2]=(unsigned)q4[32]|((unsigned)q5[32]<<16);
      b2.u[3]=(unsigned)q6[32]|((unsigned)q7[32]<<16);
      b3.u[0]=(unsigned)q0[48]|((unsigned)q1[48]<<16);
      b3.u[1]=(unsigned)q2[48]|((unsigned)q3[48]<<16);
      b3.u[2]=(unsigned)q4[48]|((unsigned)q5[48]<<16);
      b3.u[3]=(unsigned)q6[48]|((unsigned)q7[48]<<16);
      acc0 = __builtin_amdgcn_mfma_f32_16x16x32_bf16(af.v, b0.v, acc0, 0,0,0);
      acc1 = __builtin_amdgcn_mfma_f32_16x16x32_bf16(af.v, b1.v, acc1, 0,0,0);
      acc2 = __builtin_amdgcn_mfma_f32_16x16x32_bf16(af.v, b2.v, acc2, 0,0,0);
      acc3 = __builtin_amdgcn_mfma_f32_16x16x32_bf16(af.v, b3.v, acc3, 0,0,0);
    }
    // lane (m,kq): acc_f[ri] = z[node (wv*4+kq)][head ri][dim f*16+m]
    unsigned short* zrow = Zl + (wv*4+kq)*LZS + r*256 + m*4;
    ushort4 o;
    o.x=f2bf(acc0[0]); o.y=f2bf(acc0[1]); o.z=f2bf(acc0[2]); o.w=f2bf(acc0[3]);
    *(ushort4*)(zrow)       = o;
    o.x=f2bf(acc1[0]); o.y=f2bf(acc1[1]); o.z=f2bf(acc1[2]); o.w=f2bf(acc1[3]);
    *(ushort4*)(zrow + 64)  = o;
    o.x=f2bf(acc2[0]); o.y=f2bf(acc2[1]); o.z=f2bf(acc2[2]); o.w=f2bf(acc2[3]);
    *(ushort4*)(zrow + 128) = o;
    o.x=f2bf(acc3[0]); o.y=f2bf(acc3[1]); o.z=f2bf(acc3[2]); o.w=f2bf(acc3[3]);
    *(ushort4*)(zrow + 192) = o;
    int degk = __shfl((int)dg, kq<<2, 64);  // degree of node n4+kq
    if(m==0)
      Zl[(wv*4+kq)*LZS + 768 + r] = degk>0 ? (unsigned short)0x3F80 : (unsigned short)0;
  }
  __syncthreads();
  // ---- phase 2: fused matmul, wave wv -> col-tile wv ----
  floatx4 acc = {0.f,0.f,0.f,0.f};
  const unsigned short* Arow = Abf + (size_t)(nb+m)*64;
  const unsigned short* Zrow = Zl + m*LZS;
  #pragma unroll
  for(int kb=0; kb<27; kb++){
    short8 a;
    if(kb<2) a = *(const short8*)(Arow + kb*32 + kq*8);
    else     a = *(const short8*)(Zrow + (kb-2)*32 + kq*8);
    short8 b = *(const short8*)(Wf + (size_t)(wv*16+m)*KTOT + kb*32 + kq*8);
    acc = __builtin_amdgcn_mfma_f32_16x16x32_bf16(a, b, acc, 0,0,0);
  }
  int col = wv*16 + m;
  float bb = biasF[col];
  float sv=0.f, qv=0.f;
  #pragma unroll
  for(int ri=0; ri<4; ri++){
    int ro = nb + kq*4 + ri;
    float v = fmaxf(acc[ri] + bb, 0.f);
    out[(size_t)ro*64 + col] = v;
    if(dostats){
      Abf2[(size_t)ro*64 + col] = f2bf(v);
      sv += v; qv += v*v;
    }
  }
  if(dostats){
    sv += __shfl_xor(sv, 16, 64); qv += __shfl_xor(qv, 16, 64);
    sv += __shfl_xor(sv, 32, 64); qv += __shfl_xor(qv, 32, 64);
    if(kq==0){ atomicAdd(&stats[col], sv); atomicAdd(&stats[64+col], qv); }
  }
}

extern "C" void kernel_launch(void* const* d_in, const int* in_sizes, int n_in,
                              void* d_out, int out_size, void* d_ws, size_t ws_size,
                              hipStream_t stream){
  const float* x      =(const float*)d_in[0];
  const int* src_res  =(const int*)d_in[1];
  const int* dst_res  =(const int*)d_in[2];
  const int* src_seq  =(const int*)d_in[3];
  const int* dst_seq  =(const int*)d_in[4];
  const int* src_knn  =(const int*)d_in[5];
  const int* dst_knn  =(const int*)d_in[6];
  const float* W0 =(const float*)d_in[7];
  const float* al0=(const float*)d_in[8];
  const float* ar0=(const float*)d_in[9];
  const float* b0 =(const float*)d_in[10];
  const float* rW0=(const float*)d_in[11];
  const float* W1 =(const float*)d_in[12];
  const float* al1=(const float*)d_in[13];
  const float* ar1=(const float*)d_in[14];
  const float* b1 =(const float*)d_in[15];
  const float* rW1=(const float*)d_in[16];
  const float* fcW0=(const float*)d_in[17];
  const float* fcb0=(const float*)d_in[18];
  const float* fcW1=(const float*)d_in[19];
  const float* fcb1=(const float*)d_in[20];
  const float* g0 =(const float*)d_in[21];
  const float* be0=(const float*)d_in[22];
  const float* g1 =(const float*)d_in[23];
  const float* be1=(const float*)d_in[24];

  char* ws=(char*)d_ws;
  int*   bcnt   =(int*)  (ws+0);               // 294 ints (zeroed by memset)
  int*   bbase  =(int*)  (ws+4096);            // 295 ints
  float* stats0 =(float*)(ws+600000);
  float* stats1 =(float*)(ws+600512);
  int*   rowptr =(int*)  (ws+601024);          // 3*RPS ints
  int*   bcur   =(int*)  (ws+1201088);         // 294 ints
  int*   csr    =(int*)  (ws+1801088);         // 900000 ints
  float* wbuf   =(float*)(ws+5401088);         // ~117 KB
  unsigned short* Abf  =(unsigned short*)(ws+5526528);   // NN*64 bf16 = 6.4MB
  unsigned* pairs =(unsigned*)(ws+27000000UL); // 3.6MB staging
  float* xbuf   =(float*)(ws+91926528UL);      // NN*64 f32
  float* EL     =(float*)(ws+104726528UL);     // 3*NN*8 f32
  unsigned short* coefT=(unsigned short*)(ws+109526528UL); // 4 planes x CTPS = 7.2MB
  unsigned short* Abf2 =(unsigned short*)(ws+123926528UL); // NN*64 bf16 (layer-2 A)

  hipMemsetAsync(ws, 0, 601024, stream);  // bcnt + stats buffers

  // ---- bucketed CSR build ----
  k_bucketcnt<<<PABLK,256,0,stream>>>(dst_res,dst_seq,dst_knn,bcnt);
  k_bucketscan<<<1,512,0,stream>>>(bcnt,bbase,bcur);
  k_partA<<<PABLK,256,0,stream>>>(src_res,dst_res,src_seq,dst_seq,
                                  src_knn,dst_knn,bcur,pairs);
  k_partB<<<TBUK,256,0,stream>>>(pairs,bbase,rowptr,csr);

  // ---- layer 1 ----
  k_bnstats<<<256,256,0,stream>>>(x,stats0,Abf);
  k_prep3<<<59,256,0,stream>>>(stats0,g0,be0,W0,al0,ar0,b0,rW0,fcW0,fcb0,wbuf);
  k_el3<<<3*NBLK,256,0,stream>>>(x,wbuf,EL);
  k_edgecoef3<<<ECB,256,0,stream>>>(EL,rowptr,csr,coefT);
  k_fused<<<FBLK,256,0,stream>>>(Abf,rowptr,csr,coefT,wbuf,xbuf,Abf2,stats1,1);
  // ---- layer 2 ----
  k_prep3<<<59,256,0,stream>>>(stats1,g1,be1,W1,al1,ar1,b1,rW1,fcW1,fcb1,wbuf);
  k_el3<<<3*NBLK,256,0,stream>>>(xbuf,wbuf,EL);
  k_edgecoef3<<<ECB,256,0,stream>>>(EL,rowptr,csr,coefT);
  k_fused<<<FBLK,256,0,stream>>>(Abf2,rowptr,csr,coefT,wbuf,(float*)d_out,Abf2,stats0,0);
}

// Round 10
// 409.009 us; speedup vs baseline: 1.2776x; 1.2776x over previous
//
#include <hip/hip_runtime.h>
#include <math.h>

#define NN    50000
#define DD    64
#define HH    4
#define E_RES 400000
#define E_SEQ 100000
#define E_KNN 400000
#define ETOT  (E_RES+E_SEQ+E_KNN)
#define RPS   (NN + 4)               // rowptr stride (16B-aligned per relation)
#define NBLK  ((NN+255)/256)         // 196
#define KTOT  864                    // fused matmul K: 64 (x) + 800 (z+flags+pad)
#define CTPS  (ETOT + 32)            // coefT per-head plane stride (shorts)
#define NBUK  98                     // buckets per relation (512 dsts each)
#define TBUK  (3*NBUK)               // 294 total buckets
#define EPB   4096                   // edges per block in partition kernels
#define PABLK ((ETOT+EPB-1)/EPB)     // 220
#define FBLK  (NN/16)                // 3125 fused blocks (16 nodes each)
#define ECB2  ((3*NN + 31)/32)       // 4688 edgecoef blocks (32 items each)
#define LZS   810                    // LDS Z stride in shorts (405 dwords, odd -> bank-safe)

typedef __attribute__((ext_vector_type(8))) short short8;
typedef __attribute__((ext_vector_type(4))) float floatx4;

__device__ inline unsigned short f2bf(float f){
  union{float f; unsigned u;} v; v.f=f;
  unsigned r = v.u + 0x7FFF + ((v.u>>16)&1);
  return (unsigned short)(r>>16);
}
__device__ inline float bf2f(unsigned short u){
  union{unsigned u; float f;} v; v.u=(unsigned)u<<16; return v.f;
}

// ---------------- bucketed CSR build --------------------------------------
__global__ void __launch_bounds__(256)
k_bucketcnt(const int* __restrict__ d0, const int* __restrict__ d1,
            const int* __restrict__ d2, int* __restrict__ bcnt){
  __shared__ int cnt[TBUK];
  int t = threadIdx.x;
  for(int i=t;i<TBUK;i+=256) cnt[i]=0;
  __syncthreads();
  int ebase = blockIdx.x*EPB;
  #pragma unroll
  for(int j=0;j<16;j++){
    int i = ebase + j*256 + t;
    int d, r;
    if(i < E_RES){ d=d0[i]; r=0; }
    else if(i < E_RES+E_SEQ){ d=d1[i-E_RES]; r=1; }
    else if(i < ETOT){ d=d2[i-E_RES-E_SEQ]; r=2; }
    else continue;
    atomicAdd(&cnt[r*NBUK + (d>>9)], 1);
  }
  __syncthreads();
  for(int i=t;i<TBUK;i+=256){ int c=cnt[i]; if(c) atomicAdd(&bcnt[i], c); }
}

__global__ void k_bucketscan(const int* __restrict__ bcnt,
                             int* __restrict__ bbase, int* __restrict__ bcur){
  __shared__ int sh[TBUK];
  int t = threadIdx.x;
  if(t < 64){
    int carry = 0;
    for(int c=0;c<5;c++){
      int idx = c*64 + t;
      int v = (idx < TBUK) ? bcnt[idx] : 0;
      int inc = v;
      for(int off=1; off<64; off<<=1){ int n=__shfl_up(inc, off, 64); if(t>=off) inc+=n; }
      if(idx < TBUK) sh[idx] = carry + inc - v;   // exclusive
      carry += __shfl(inc, 63, 64);
    }
  }
  __syncthreads();
  if(t < TBUK){ bbase[t] = sh[t]; bcur[t] = sh[t]; }
  if(t == 0) bbase[TBUK] = ETOT;
}

// partition edges into bucket regions as packed (dloc<<16 | src) u32
__global__ void __launch_bounds__(256)
k_partA(const int* __restrict__ s0, const int* __restrict__ d0,
        const int* __restrict__ s1, const int* __restrict__ d1,
        const int* __restrict__ s2, const int* __restrict__ d2,
        int* __restrict__ bcur, unsigned* __restrict__ pairs){
  __shared__ int cnt[TBUK];
  __shared__ int gb[TBUK];
  int t = threadIdx.x;
  for(int i=t;i<TBUK;i+=256) cnt[i]=0;
  __syncthreads();
  int ebase = blockIdx.x*EPB;
  unsigned meta[16], pk[16];
  #pragma unroll
  for(int j=0;j<16;j++){
    int i = ebase + j*256 + t;
    int s, d, r;
    if(i < E_RES){ s=s0[i]; d=d0[i]; r=0; }
    else if(i < E_RES+E_SEQ){ int k=i-E_RES; s=s1[k]; d=d1[k]; r=1; }
    else if(i < ETOT){ int k=i-E_RES-E_SEQ; s=s2[k]; d=d2[k]; r=2; }
    else { meta[j]=0xFFFFFFFFu; continue; }
    int bk = r*NBUK + (d>>9);
    int rk = atomicAdd(&cnt[bk], 1);
    meta[j] = ((unsigned)bk<<16) | (unsigned)rk;   // bk<294, rk<4096
    pk[j]   = ((unsigned)(d&511)<<16) | (unsigned)s;  // src < 65536
  }
  __syncthreads();
  for(int i=t;i<TBUK;i+=256){ int c=cnt[i]; gb[i] = c ? atomicAdd(&bcur[i], c) : 0; }
  __syncthreads();
  #pragma unroll
  for(int j=0;j<16;j++){
    unsigned mt = meta[j];
    if(mt != 0xFFFFFFFFu)
      pairs[gb[mt>>16] + (mt & 0xFFFFu)] = pk[j];
  }
}

// per-bucket: LDS per-dst histogram -> rowptr slice + localized csr scatter
__global__ void __launch_bounds__(256)
k_partB(const unsigned* __restrict__ pairs, const int* __restrict__ bbase,
        int* __restrict__ rowptr, int* __restrict__ csr){
  int bb = blockIdx.x, r = bb / NBUK, b = bb - r*NBUK;
  int dbase = b*512, dmax = min(512, NN - dbase);
  int off = (r==0)?0:(r==1)?E_RES:(E_RES+E_SEQ);
  __shared__ int hist[512];
  __shared__ int curs[513];
  int t = threadIdx.x;
  hist[t]=0; hist[256+t]=0;
  __syncthreads();
  int beg = bbase[bb], end = bbase[bb+1];
  for(int i=beg+t; i<end; i+=256) atomicAdd(&hist[pairs[i]>>16], 1);
  __syncthreads();
  if(t < 64){
    int carry = 0;
    for(int c=0;c<8;c++){
      int v = hist[c*64+t];
      int inc = v;
      for(int o2=1; o2<64; o2<<=1){ int n=__shfl_up(inc, o2, 64); if(t>=o2) inc+=n; }
      curs[c*64+t] = (beg - off) + carry + inc - v;   // exclusive, relation-local
      carry += __shfl(inc, 63, 64);
    }
    if(t==0) curs[512] = end - off;
  }
  __syncthreads();
  int* rp = rowptr + r*RPS + dbase;
  for(int i=t; i<=dmax; i+=256) rp[i] = curs[i];
  __syncthreads();
  for(int i=beg+t; i<end; i+=256){
    unsigned p = pairs[i];
    int pos = atomicAdd(&curs[p>>16], 1);
    csr[off + pos] = (int)(p & 0xFFFFu);
  }
}

// ---------------- BN stats + bf16 cast (layer 1 input) ----------------------
__global__ void k_bnstats(const float* __restrict__ x, float* __restrict__ stats,
                          unsigned short* __restrict__ Abf){
  __shared__ float sh[512];
  int t = threadIdx.x, col = t & 63, rg = t >> 6;
  float s=0.f, q=0.f;
  for(int row = blockIdx.x*4 + rg; row < NN; row += gridDim.x*4){
    float v = x[(size_t)row*64 + col]; s += v; q += v*v;
    Abf[(size_t)row*64 + col] = f2bf(v);
  }
  sh[t]=s; sh[256+t]=q; __syncthreads();
  if(rg==0){
    s = sh[col]+sh[64+col]+sh[128+col]+sh[192+col];
    q = sh[256+col]+sh[320+col]+sh[384+col]+sh[448+col];
    atomicAdd(&stats[col], s); atomicAdd(&stats[64+col], q);
  }
}

// ---------------- prep: build fused weights ---------------------------------
// Z K-layout (shorts within a node row): [r][d][h]  (d = z input dim, h = head)
// => K index for z element = 64 + r*256 + d*4 + h.  Flags at 832+r. Pad zero.
__global__ void __launch_bounds__(256)
k_prep3(const float* __restrict__ stats, const float* __restrict__ g,
        const float* __restrict__ be, const float* __restrict__ W,
        const float* __restrict__ al, const float* __restrict__ ar,
        const float* __restrict__ b, const float* __restrict__ rW,
        const float* __restrict__ fcW, const float* __restrict__ fcb,
        float* __restrict__ wbufF){
  __shared__ float scale[64], shift[64];
  int t = threadIdx.x;
  if(t<64){
    float mu  = stats[t]*(1.0f/NN);
    float var = stats[64+t]*(1.0f/NN) - mu*mu;
    float sc  = g[t]*rsqrtf(var + 1e-5f);
    scale[t]=sc; shift[t]=be[t]-mu*sc;
  }
  __syncthreads();
  char* wb = (char*)wbufF;
  unsigned short* Wf = (unsigned short*)wbufF;
  float* biasF = (float*)(wb + 110592);
  int bid = blockIdx.x;
  if(bid < 52){
    __shared__ float fcWs[4096];
    for(int i=t;i<4096;i+=256) fcWs[i]=fcW[i];
    __syncthreads();
    int j = bid*16 + (t>>4);
    int cg = (t&15)*4;
    float Wrow[64];
    if(j < 64){
      for(int d=0; d<64; d++){
        float w=0.f;
        for(int r=0;r<3;r++)
          #pragma unroll
          for(int h=0;h<4;h++)
            w += rW[((size_t)(r*64+j))*256 + h*64 + d];
        Wrow[d] = scale[j]*0.25f*w;
      }
    } else {
      int jj = j-64;
      int r = jj>>8, dc = jj&255, h = dc&3, c = dc>>2;   // [r][d][h] K-layout
      const float* Wp = W + ((size_t)(r*64+c))*256 + h*64;
      float sc = 0.25f*scale[c];
      #pragma unroll
      for(int d=0; d<64; d++) Wrow[d] = sc*Wp[d];
    }
    #pragma unroll
    for(int cc=0; cc<4; cc++){
      int col = cg+cc;
      float acc=0.f;
      #pragma unroll
      for(int d=0; d<64; d++) acc += Wrow[d]*fcWs[d*64+col];
      Wf[(size_t)col*KTOT + j] = f2bf(acc);
    }
  } else if(bid < 58){
    int wv = (bid-52)*4 + (t>>6);        // 0..23
    int r = wv >> 3, cc = wv & 7, h = cc & 3, k = t & 63;
    const float* av = ((cc>=4)?ar:al) + (r*HH+h)*64;
    const float* Wk = W + ((size_t)(r*64+k))*256 + h*64;
    float w=0.f;
    for(int d2=0; d2<64; d2++) w += Wk[d2]*av[d2];
    float* WelR = (float*)(wb + 110848 + r*2080);
    WelR[cc*64 + k] = scale[k]*w;
    float bp = shift[k]*w;
    for(int off=32; off; off>>=1) bp += __shfl_down(bp, off, 64);
    if(k==0) (WelR + 512)[cc] = bp;
  } else {
    __shared__ float S[3][64];
    __shared__ float BH[64];
    if(t<192){
      int r=t>>6, d=t&63;
      float s=0.f;
      #pragma unroll
      for(int h=0;h<4;h++){
        const float* Wp = W + (size_t)(r*64)*256 + h*64 + d;
        for(int k=0;k<64;k++) s += shift[k]*Wp[(size_t)k*256];
      }
      S[r][d]=0.25f*s;
    } else {
      int d = t-192;
      float s=0.f;
      for(int k=0;k<64;k++){
        float w=0.f;
        for(int r=0;r<3;r++)
          #pragma unroll
          for(int h=0;h<4;h++)
            w += rW[((size_t)(r*64+k))*256 + h*64 + d];
        s += shift[k]*0.25f*w;
      }
      float bb=0.f;
      for(int r=0;r<3;r++)
        #pragma unroll
        for(int h=0;h<4;h++) bb += b[r*256 + h*64 + d];
      BH[d] = s + 0.25f*bb;
    }
    __syncthreads();
    if(t<192){
      int r=t>>6, col=t&63;
      float acc=0.f;
      for(int d=0;d<64;d++) acc += S[r][d]*fcW[d*64+col];
      Wf[(size_t)col*KTOT + 832 + r] = f2bf(acc);
    } else {
      int col=t-192;
      float acc=0.f;
      for(int d=0;d<64;d++) acc += BH[d]*fcW[d*64+col];
      biasF[col] = acc + fcb[col];
    }
    if(t<64){
      for(int j=835;j<KTOT;j++) Wf[(size_t)t*KTOT + j] = 0;
    }
  }
}

// ---------------- el/er (all 3 relations): EL[r][N,8] -----------------------
__global__ void __launch_bounds__(256)
k_el3(const float* __restrict__ A, const float* __restrict__ wbufF,
      float* __restrict__ EL){
  int r = blockIdx.x / NBLK;
  const char* wb = (const char*)wbufF;
  const float* Wel = (const float*)(wb + 110848 + r*2080);
  const float* biasE = Wel + 512;
  float* ELr = EL + (size_t)r*NN*8;
  __shared__ float sw[512];
  __shared__ float sb[8];
  int t = threadIdx.x;
  sw[t]=Wel[t]; sw[256+t]=Wel[256+t];
  if(t<8) sb[t]=biasE[t];
  __syncthreads();
  int n = (blockIdx.x % NBLK)*256 + t;
  if(n>=NN) return;
  float acc[8];
  #pragma unroll
  for(int c=0;c<8;c++) acc[c]=sb[c];
  const float4* Ar = (const float4*)(A + (size_t)n*64);
  #pragma unroll
  for(int kq=0;kq<16;kq++){
    float4 a = Ar[kq];
    #pragma unroll
    for(int c=0;c<8;c++){
      const float* w = sw + c*64 + kq*4;
      acc[c] += a.x*w[0] + a.y*w[1] + a.z*w[2] + a.w*w[3];
    }
  }
  ((float4*)ELr)[n*2]   = make_float4(acc[0],acc[1],acc[2],acc[3]);
  ((float4*)ELr)[n*2+1] = make_float4(acc[4],acc[5],acc[6],acc[7]);
}

// ---------------- edge coefficients: 8-LANE GROUP per (node, relation) ------
// r9's wave-per-item wasted 56/64 lanes (mean deg=8). Now 8 lanes per item:
// wave = 8 items, 18750 waves (8x the serial version's 2344). Lane sl handles
// edges beg+sl+8c; chunks c<4 (deg<=32, ~all nodes) are register-cached so the
// alpha pass needs NO second gather. Cross-lane online-softmax combine over
// xor {1,2,4} stays in-group. deg>32 overflow: re-gather loop (correctness).
#define EC_GATHER(ii, E0,E1,E2,E3) { \
    int src_ = cs[ii]; \
    float4 el_ = ((const float4*)ELr)[src_*2]; \
    E0=el_.x+er.x; E1=el_.y+er.y; E2=el_.z+er.z; E3=el_.w+er.w; \
    E0 = E0>0.f? E0 : 0.2f*E0; \
    E1 = E1>0.f? E1 : 0.2f*E1; \
    E2 = E2>0.f? E2 : 0.2f*E2; \
    E3 = E3>0.f? E3 : 0.2f*E3; }
#define EC_ACC(E0,E1,E2,E3) { \
    float n0_=fmaxf(m0,E0); s0=s0*__expf(m0-n0_)+__expf(E0-n0_); m0=n0_; \
    float n1_=fmaxf(m1,E1); s1=s1*__expf(m1-n1_)+__expf(E1-n1_); m1=n1_; \
    float n2_=fmaxf(m2,E2); s2=s2*__expf(m2-n2_)+__expf(E2-n2_); m2=n2_; \
    float n3_=fmaxf(m3,E3); s3=s3*__expf(m3-n3_)+__expf(E3-n3_); m3=n3_; }
#define EC_COMB(o) { \
    float om_,os_,nm_; \
    om_=__shfl_xor(m0,o,64); os_=__shfl_xor(s0,o,64); \
    nm_=fmaxf(m0,om_); s0=s0*__expf(m0-nm_)+os_*__expf(om_-nm_); m0=nm_; \
    om_=__shfl_xor(m1,o,64); os_=__shfl_xor(s1,o,64); \
    nm_=fmaxf(m1,om_); s1=s1*__expf(m1-nm_)+os_*__expf(om_-nm_); m1=nm_; \
    om_=__shfl_xor(m2,o,64); os_=__shfl_xor(s2,o,64); \
    nm_=fmaxf(m2,om_); s2=s2*__expf(m2-nm_)+os_*__expf(om_-nm_); m2=nm_; \
    om_=__shfl_xor(m3,o,64); os_=__shfl_xor(s3,o,64); \
    nm_=fmaxf(m3,om_); s3=s3*__expf(m3-nm_)+os_*__expf(om_-nm_); m3=nm_; }
#define EC_STORE(ii, E0,E1,E2,E3) { \
    t0[ii]=f2bf(__expf(E0-m0)*r0); t1[ii]=f2bf(__expf(E1-m1)*r1); \
    t2[ii]=f2bf(__expf(E2-m2)*r2); t3[ii]=f2bf(__expf(E3-m3)*r3); }

__global__ void __launch_bounds__(256)
k_edgecoef3(const float* __restrict__ EL, const int* __restrict__ rowptr,
            const int* __restrict__ csr, unsigned short* __restrict__ coefT){
  int item = blockIdx.x*32 + (threadIdx.x>>3);
  int sl = threadIdx.x & 7;
  if(item >= 3*NN) return;
  int r = item / NN, n = item - r*NN;
  const float* ELr = EL + (size_t)r*NN*8;
  const int* rp = rowptr + r*RPS;
  int off = (r==0)?0:(r==1)?E_RES:(E_RES+E_SEQ);
  const int* cs = csr + off;
  unsigned short* t0 = coefT + off;
  unsigned short* t1 = coefT + (size_t)CTPS + off;
  unsigned short* t2 = coefT + (size_t)2*CTPS + off;
  unsigned short* t3 = coefT + (size_t)3*CTPS + off;
  int beg = rp[n], end = rp[n+1];
  if(end <= beg) return;
  const float4 er = ((const float4*)ELr)[n*2+1];
  float m0=-1e30f,m1=-1e30f,m2=-1e30f,m3=-1e30f;
  float s0=0.f,s1=0.f,s2=0.f,s3=0.f;
  int i0 = beg + sl, i1 = i0 + 8, i2 = i0 + 16, i3 = i0 + 24;
  bool h0 = i0 < end, h1 = i1 < end, h2 = i2 < end, h3 = i3 < end;
  float a0=0.f,a1=0.f,a2=0.f,a3=0.f;
  float b0=0.f,b1=0.f,b2=0.f,b3=0.f;
  float c0=0.f,c1=0.f,c2=0.f,c3=0.f;
  float d0=0.f,d1=0.f,d2=0.f,d3=0.f;
  if(h0){ EC_GATHER(i0, a0,a1,a2,a3); EC_ACC(a0,a1,a2,a3); }
  if(h1){ EC_GATHER(i1, b0,b1,b2,b3); EC_ACC(b0,b1,b2,b3); }
  if(h2){ EC_GATHER(i2, c0,c1,c2,c3); EC_ACC(c0,c1,c2,c3); }
  if(h3){ EC_GATHER(i3, d0,d1,d2,d3); EC_ACC(d0,d1,d2,d3); }
  for(int i = i0 + 32; i < end; i += 8){
    float e0,e1,e2,e3;
    EC_GATHER(i, e0,e1,e2,e3);
    EC_ACC(e0,e1,e2,e3);
  }
  EC_COMB(1) EC_COMB(2) EC_COMB(4)
  float r0=1.f/s0, r1=1.f/s1, r2=1.f/s2, r3=1.f/s3;
  if(h0) EC_STORE(i0, a0,a1,a2,a3);
  if(h1) EC_STORE(i1, b0,b1,b2,b3);
  if(h2) EC_STORE(i2, c0,c1,c2,c3);
  if(h3) EC_STORE(i3, d0,d1,d2,d3);
  for(int i = i0 + 32; i < end; i += 8){
    float e0,e1,e2,e3;
    EC_GATHER(i, e0,e1,e2,e3);
    EC_STORE(i, e0,e1,e2,e3);
  }
}

// ---------------- FUSED aggregation + matmul (r7 best-measured form) --------
// Block = 4 waves = 16 nodes. Phase 1: wave wv aggregates Z for its 4-node
// group across 3 relations via MFMA into LDS (LZS=810 conflict-free). Phase 2:
// wave wv -> col-tile wv, K=864 matmul. ~100us/layer floor measured stable
// across 5 structural variants (occupancy/wave-length/VMEM-count theories all
// falsified) — treat as floor, do not restructure.
__global__ void __launch_bounds__(256)
k_fused(const unsigned short* __restrict__ Abf, const int* __restrict__ rowptr,
        const int* __restrict__ csr, const unsigned short* __restrict__ coefT,
        const float* __restrict__ wbufF, float* __restrict__ out,
        unsigned short* __restrict__ Abf2, float* __restrict__ stats, int dostats){
  __shared__ unsigned short Zl[16*LZS];   // 25920 B
  const unsigned short* Wf = (const unsigned short*)wbufF;
  const float* biasF = (const float*)((const char*)wbufF + 110592);
  int t = threadIdx.x, wv = t>>6, lane = t&63, m = lane&15, kq = lane>>4;
  int nb = blockIdx.x*16;
  int n4 = nb + wv*4;
  int nn = m>>2, h = m&3;
  // zero pad shorts [771,800) of each node row (phase 2 reads shorts [0,800))
  for(int i=t; i<512; i+=256){ int nd=i>>5, j=i&31; if(j<29) Zl[nd*LZS+771+j]=0; }
  // ---- phase 1: aggregation (3 relations sequentially) ----
  for(int r=0;r<3;r++){
    const int* rp = rowptr + r*RPS;
    int off = (r==0)?0:(r==1)?E_RES:(E_RES+E_SEQ);
    const int* cs = csr + off;
    const unsigned short* cT = coefT + (size_t)h*CTPS + off;
    int rpn  = rp[n4+nn];
    int rpn1 = rp[n4+nn+1];
    unsigned dg = (unsigned)(rpn1 - rpn);
    int beg = __shfl(rpn, 0, 64);     // rp[n4]
    int end = __shfl(rpn1, 15, 64);   // rp[n4+4]
    floatx4 acc0={0.f,0.f,0.f,0.f};
    floatx4 acc1={0.f,0.f,0.f,0.f};
    floatx4 acc2={0.f,0.f,0.f,0.f};
    floatx4 acc3={0.f,0.f,0.f,0.f};
    for(int eb = (beg & ~31); eb < end; eb += 32){
      int p0 = eb + kq*8;
      union { uint4 q; short8 v; } af;
      af.q = *(const uint4*)(cT + p0);
      int qd = p0 - rpn;
      unsigned w0 = (((unsigned)(qd+0)<dg)?0x0000FFFFu:0u) | (((unsigned)(qd+1)<dg)?0xFFFF0000u:0u);
      unsigned w1 = (((unsigned)(qd+2)<dg)?0x0000FFFFu:0u) | (((unsigned)(qd+3)<dg)?0xFFFF0000u:0u);
      unsigned w2 = (((unsigned)(qd+4)<dg)?0x0000FFFFu:0u) | (((unsigned)(qd+5)<dg)?0xFFFF0000u:0u);
      unsigned w3 = (((unsigned)(qd+6)<dg)?0x0000FFFFu:0u) | (((unsigned)(qd+7)<dg)?0xFFFF0000u:0u);
      af.q.x &= w0; af.q.y &= w1; af.q.z &= w2; af.q.w &= w3;
      const int* csp = cs + p0;
      int s0=csp[0],s1=csp[1],s2=csp[2],s3=csp[3],s4=csp[4],s5=csp[5],s6=csp[6],s7=csp[7];
      const unsigned short* q0 = Abf + ((size_t)s0<<6) + m;
      const unsigned short* q1 = Abf + ((size_t)s1<<6) + m;
      const unsigned short* q2 = Abf + ((size_t)s2<<6) + m;
      const unsigned short* q3 = Abf + ((size_t)s3<<6) + m;
      const unsigned short* q4 = Abf + ((size_t)s4<<6) + m;
      const unsigned short* q5 = Abf + ((size_t)s5<<6) + m;
      const unsigned short* q6 = Abf + ((size_t)s6<<6) + m;
      const unsigned short* q7 = Abf + ((size_t)s7<<6) + m;
      union { unsigned u[4]; short8 v; } b0,b1,b2,b3;
      b0.u[0]=(unsigned)q0[0] |((unsigned)q1[0]<<16);
      b0.u[1]=(unsigned)q2[0] |((unsigned)q3[0]<<16);
      b0.u[2]=(unsigned)q4[0] |((unsigned)q5[0]<<16);
      b0.u[3]=(unsigned)q6[0] |((unsigned)q7[0]<<16);
      b1.u[0]=(unsigned)q0[16]|((unsigned)q1[16]<<16);
      b1.u[1]=(unsigned)q2[16]|((unsigned)q3[16]<<16);
      b1.u[2]=(unsigned)q4[16]|((unsigned)q5[16]<<16);
      b1.u[3]=(unsigned)q6[16]|((unsigned)q7[16]<<16);
      b2.u[0]=(unsigned)q0[32]|((unsigned)q1[32]<<16);
      b2.u[1]=(unsigned)q2[32]|((unsigned)q3[32]<<16);
      b2.u[2]=(unsigned)q4[32]|((unsigned)q5[32]<<16);
      b2.u[3]=(unsigned)q6[32]|((unsigned)q7[32]<<16);
      b3.u[0]=(unsigned)q0[48]|((unsigned)q1[48]<<16);
      b3.u[1]=(unsigned)q2[48]|((unsigned)q3[48]<<16);
      b3.u[2]=(unsigned)q4[48]|((unsigned)q5[48]<<16);
      b3.u[3]=(unsigned)q6[48]|((unsigned)q7[48]<<16);
      acc0 = __builtin_amdgcn_mfma_f32_16x16x32_bf16(af.v, b0.v, acc0, 0,0,0);
      acc1 = __builtin_amdgcn_mfma_f32_16x16x32_bf16(af.v, b1.v, acc1, 0,0,0);
      acc2 = __builtin_amdgcn_mfma_f32_16x16x32_bf16(af.v, b2.v, acc2, 0,0,0);
      acc3 = __builtin_amdgcn_mfma_f32_16x16x32_bf16(af.v, b3.v, acc3, 0,0,0);
    }
    // lane (m,kq): acc_f[ri] = z[node (wv*4+kq)][head ri][dim f*16+m]
    unsigned short* zrow = Zl + (wv*4+kq)*LZS + r*256 + m*4;
    ushort4 o;
    o.x=f2bf(acc0[0]); o.y=f2bf(acc0[1]); o.z=f2bf(acc0[2]); o.w=f2bf(acc0[3]);
    *(ushort4*)(zrow)       = o;
    o.x=f2bf(acc1[0]); o.y=f2bf(acc1[1]); o.z=f2bf(acc1[2]); o.w=f2bf(acc1[3]);
    *(ushort4*)(zrow + 64)  = o;
    o.x=f2bf(acc2[0]); o.y=f2bf(acc2[1]); o.z=f2bf(acc2[2]); o.w=f2bf(acc2[3]);
    *(ushort4*)(zrow + 128) = o;
    o.x=f2bf(acc3[0]); o.y=f2bf(acc3[1]); o.z=f2bf(acc3[2]); o.w=f2bf(acc3[3]);
    *(ushort4*)(zrow + 192) = o;
    int degk = __shfl((int)dg, kq<<2, 64);  // degree of node n4+kq
    if(m==0)
      Zl[(wv*4+kq)*LZS + 768 + r] = degk>0 ? (unsigned short)0x3F80 : (unsigned short)0;
  }
  __syncthreads();
  // ---- phase 2: fused matmul, wave wv -> col-tile wv ----
  floatx4 acc = {0.f,0.f,0.f,0.f};
  const unsigned short* Arow = Abf + (size_t)(nb+m)*64;
  const unsigned short* Zrow = Zl + m*LZS;
  #pragma unroll
  for(int kb=0; kb<27; kb++){
    short8 a;
    if(kb<2) a = *(const short8*)(Arow + kb*32 + kq*8);
    else     a = *(const short8*)(Zrow + (kb-2)*32 + kq*8);
    short8 b = *(const short8*)(Wf + (size_t)(wv*16+m)*KTOT + kb*32 + kq*8);
    acc = __builtin_amdgcn_mfma_f32_16x16x32_bf16(a, b, acc, 0,0,0);
  }
  int col = wv*16 + m;
  float bb = biasF[col];
  float sv=0.f, qv=0.f;
  #pragma unroll
  for(int ri=0; ri<4; ri++){
    int ro = nb + kq*4 + ri;
    float v = fmaxf(acc[ri] + bb, 0.f);
    out[(size_t)ro*64 + col] = v;
    if(dostats){
      Abf2[(size_t)ro*64 + col] = f2bf(v);
      sv += v; qv += v*v;
    }
  }
  if(dostats){
    sv += __shfl_xor(sv, 16, 64); qv += __shfl_xor(qv, 16, 64);
    sv += __shfl_xor(sv, 32, 64); qv += __shfl_xor(qv, 32, 64);
    if(kq==0){ atomicAdd(&stats[col], sv); atomicAdd(&stats[64+col], qv); }
  }
}

extern "C" void kernel_launch(void* const* d_in, const int* in_sizes, int n_in,
                              void* d_out, int out_size, void* d_ws, size_t ws_size,
                              hipStream_t stream){
  const float* x      =(const float*)d_in[0];
  const int* src_res  =(const int*)d_in[1];
  const int* dst_res  =(const int*)d_in[2];
  const int* src_seq  =(const int*)d_in[3];
  const int* dst_seq  =(const int*)d_in[4];
  const int* src_knn  =(const int*)d_in[5];
  const int* dst_knn  =(const int*)d_in[6];
  const float* W0 =(const float*)d_in[7];
  const float* al0=(const float*)d_in[8];
  const float* ar0=(const float*)d_in[9];
  const float* b0 =(const float*)d_in[10];
  const float* rW0=(const float*)d_in[11];
  const float* W1 =(const float*)d_in[12];
  const float* al1=(const float*)d_in[13];
  const float* ar1=(const float*)d_in[14];
  const float* b1 =(const float*)d_in[15];
  const float* rW1=(const float*)d_in[16];
  const float* fcW0=(const float*)d_in[17];
  const float* fcb0=(const float*)d_in[18];
  const float* fcW1=(const float*)d_in[19];
  const float* fcb1=(const float*)d_in[20];
  const float* g0 =(const float*)d_in[21];
  const float* be0=(const float*)d_in[22];
  const float* g1 =(const float*)d_in[23];
  const float* be1=(const float*)d_in[24];

  char* ws=(char*)d_ws;
  int*   bcnt   =(int*)  (ws+0);               // 294 ints (zeroed by memset)
  int*   bbase  =(int*)  (ws+4096);            // 295 ints
  float* stats0 =(float*)(ws+600000);
  float* stats1 =(float*)(ws+600512);
  int*   rowptr =(int*)  (ws+601024);          // 3*RPS ints
  int*   bcur   =(int*)  (ws+1201088);         // 294 ints
  int*   csr    =(int*)  (ws+1801088);         // 900000 ints
  float* wbuf   =(float*)(ws+5401088);         // ~117 KB
  unsigned short* Abf  =(unsigned short*)(ws+5526528);   // NN*64 bf16 = 6.4MB
  unsigned* pairs =(unsigned*)(ws+27000000UL); // 3.6MB staging
  float* xbuf   =(float*)(ws+91926528UL);      // NN*64 f32
  float* EL     =(float*)(ws+104726528UL);     // 3*NN*8 f32
  unsigned short* coefT=(unsigned short*)(ws+109526528UL); // 4 planes x CTPS = 7.2MB
  unsigned short* Abf2 =(unsigned short*)(ws+123926528UL); // NN*64 bf16 (layer-2 A)

  hipMemsetAsync(ws, 0, 601024, stream);  // bcnt + stats buffers

  // ---- bucketed CSR build ----
  k_bucketcnt<<<PABLK,256,0,stream>>>(dst_res,dst_seq,dst_knn,bcnt);
  k_bucketscan<<<1,512,0,stream>>>(bcnt,bbase,bcur);
  k_partA<<<PABLK,256,0,stream>>>(src_res,dst_res,src_seq,dst_seq,
                                  src_knn,dst_knn,bcur,pairs);
  k_partB<<<TBUK,256,0,stream>>>(pairs,bbase,rowptr,csr);

  // ---- layer 1 ----
  k_bnstats<<<256,256,0,stream>>>(x,stats0,Abf);
  k_prep3<<<59,256,0,stream>>>(stats0,g0,be0,W0,al0,ar0,b0,rW0,fcW0,fcb0,wbuf);
  k_el3<<<3*NBLK,256,0,stream>>>(x,wbuf,EL);
  k_edgecoef3<<<ECB2,256,0,stream>>>(EL,rowptr,csr,coefT);
  k_fused<<<FBLK,256,0,stream>>>(Abf,rowptr,csr,coefT,wbuf,xbuf,Abf2,stats1,1);
  // ---- layer 2 ----
  k_prep3<<<59,256,0,stream>>>(stats1,g1,be1,W1,al1,ar1,b1,rW1,fcW1,fcb1,wbuf);
  k_el3<<<3*NBLK,256,0,stream>>>(xbuf,wbuf,EL);
  k_edgecoef3<<<ECB2,256,0,stream>>>(EL,rowptr,csr,coefT);
  k_fused<<<FBLK,256,0,stream>>>(Abf2,rowptr,csr,coefT,wbuf,(float*)d_out,Abf2,stats0,0);
}